// Round 7
// baseline (744.541 us; speedup 1.0000x reference)
//
#include <hip/hip_runtime.h>

typedef unsigned short u16;
typedef unsigned int   u32;
typedef unsigned long long u64;
typedef short bf16x8 __attribute__((ext_vector_type(8)));
typedef float f32x4  __attribute__((ext_vector_type(4)));

#define INF_F __builtin_inff()

__device__ __forceinline__ u16 f2bf(float f) {
  u32 u = __float_as_uint(f);
  return (u16)((u + 0x7FFFu + ((u >> 16) & 1u)) >> 16);   // RNE
}

// float -> monotonic-sortable u32 (bigger = larger float)
__device__ __forceinline__ u32 sortf(float f) {
  u32 u = __float_as_uint(f);
  return u ^ ((u32)((int)u >> 31) | 0x80000000u);
}
__device__ __forceinline__ float unsortf(u32 s) {
  u32 u = s ^ ((s & 0x80000000u) ? 0x80000000u : 0xFFFFFFFFu);
  return __uint_as_float(u);
}
__device__ __forceinline__ u64 sx64(u64 v, int m) {
  u32 lo = __shfl_xor((u32)v, m);
  u32 hi = __shfl_xor((u32)(v >> 32), m);
  return ((u64)hi << 32) | lo;
}

__device__ __forceinline__ void gload_lds16(const void* g, void* l) {
  __builtin_amdgcn_global_load_lds(
      (const __attribute__((address_space(1))) u32*)g,
      (__attribute__((address_space(3))) u32*)l, 16, 0, 0);
}

// ---------------------------------------------------------------------------
// K0: entity table fp32 -> bf16 (RNE), row-major [ne][256]. n4 = ne*64.
// ---------------------------------------------------------------------------
__global__ __launch_bounds__(256) void k0_cvt(
    const float* __restrict__ src, u16* __restrict__ dst, int n4) {
  int id = blockIdx.x * 256 + threadIdx.x;
  if (id >= n4) return;
  float4 v = ((const float4*)src)[id];
  ((ushort4*)dst)[id] = make_ushort4(f2bf(v.x), f2bf(v.y), f2bf(v.z), f2bf(v.w));
}

// ---------------------------------------------------------------------------
// K1: span_max + span_repr fp32 (+ bf16 copy for MFMA prefilter).
// grid = 1024 blocks (b,s), 256 threads.
// ---------------------------------------------------------------------------
__global__ __launch_bounds__(256) void k1_span(
    const float* __restrict__ emb, const float* __restrict__ Wsp,
    const float* __restrict__ bsp,
    float* __restrict__ out0, float* __restrict__ out1,
    u16* __restrict__ spanbf) {
  __shared__ float SM[8][256];
  __shared__ float CLS[256];
  const int bid = blockIdx.x;          // b*256 + s
  const int b = bid >> 8, s = bid & 255;
  const int t = threadIdx.x;
  const float* eb = emb + (size_t)b * 65536;

  CLS[t] = eb[t];
  if (s == 0) out0[b * 256 + t] = eb[t];

  float m = eb[s * 256 + t];
  SM[0][t] = m;
  #pragma unroll
  for (int w = 1; w < 8; ++w) {
    if (s + w < 256) m = fmaxf(m, eb[(s + w) * 256 + t]);
    SM[w][t] = m;
  }
  __syncthreads();

  float cc = 0.f;
  for (int k = 0; k < 256; k += 4) {
    float4 cq = *(const float4*)&CLS[k];
    cc += cq.x * Wsp[(size_t)(256 + k + 0) * 256 + t];
    cc += cq.y * Wsp[(size_t)(256 + k + 1) * 256 + t];
    cc += cq.z * Wsp[(size_t)(256 + k + 2) * 256 + t];
    cc += cq.w * Wsp[(size_t)(256 + k + 3) * 256 + t];
  }
  float acc[8];
  const float base = bsp[t] + cc;
  #pragma unroll
  for (int w = 0; w < 8; ++w) acc[w] = base;

  for (int k = 0; k < 256; k += 4) {
    float w0 = Wsp[(size_t)(k + 0) * 256 + t];
    float w1 = Wsp[(size_t)(k + 1) * 256 + t];
    float w2 = Wsp[(size_t)(k + 2) * 256 + t];
    float w3 = Wsp[(size_t)(k + 3) * 256 + t];
    #pragma unroll
    for (int w = 0; w < 8; ++w) {
      float4 smq = *(const float4*)&SM[w][k];
      acc[w] += smq.x * w0; acc[w] += smq.y * w1;
      acc[w] += smq.z * w2; acc[w] += smq.w * w3;
    }
  }
  const float wm = Wsp[(size_t)512 * 256 + t];
  #pragma unroll
  for (int w = 0; w < 8; ++w) {
    float val = acc[w] + (float)(w + 1) * wm;
    size_t idx = ((size_t)w * 1024 + bid) * 256 + t;
    out1[idx] = val;
    spanbf[idx] = f2bf(val);
  }
}

// ---------------------------------------------------------------------------
// K2: bf16 MFMA sims prefilter + per-row top-16, wave-parallel register slots.
// grid = 1024 blocks x 128 threads. p = blockIdx&15 (16 partitions, 3125
// ents each; p&7 = XCD -> 2 slices = 3.2 MB per XCD L2), rg = blockIdx>>4.
// 4 blocks/CU resident (LDS 40 KB) -> 8 waves/CU (2/SIMD TLP).
// Wave (2/block) holds 64 rows as 4 A-fragsets -> each B ds_read feeds 4
// MFMA. Staging: global_load_lds, pre-swizzled source / linear LDS dest,
// ring-3 chunk pipeline (chunk = 16 ents = 8 KB), DEPTH-2 prefetch:
// phase pc = {vmcnt(4); barrier; issue(pc+2) into slot freed by pc-1;
// compute(pc)}. Two compute phases (~600+ cyc) cover L2 latency.
// Slot safety: the barrier at phase pc guarantees both waves finished
// compute(pc-1), whose slot == (cs+2)%3 == the issue target. vmcnt before
// barrier => chunk pc landed for both waves after the barrier.
// Top-16 slots in registers as sortable u64 keys, 4 lanes x 4 slots/row.
// Q queue XOR-swizzled [2][64][16] (bank = 2(j^row): conflict-free);
// drain loop prefetches round j+1's Q entry while processing round j.
// Exactness restored by K3 fp64 re-rank.
// ---------------------------------------------------------------------------
__global__ __launch_bounds__(128, 2) void k2_mfma(
    const u16* __restrict__ spanbf, const u16* __restrict__ entbf, int ne,
    float* __restrict__ Rpv, int* __restrict__ Rpi) {
  __shared__ u32 Elds[6144];        // 24 KB: ring-3 x 16 ents x 256 bf16
  __shared__ u64 Q[2][64][16];      // 16 KB: per-row queue, XOR-swizzled
  const int t = threadIdx.x, lane = t & 63, wv = t >> 6;
  const int m = lane & 15, q = lane >> 4, q4 = q * 4;
  const int p = blockIdx.x & 15, rg = blockIdx.x >> 4;
  const int psz = (ne + 15) >> 4;
  const int e_start = p * psz;
  const int e_end = min(ne, e_start + psz);
  const int rowbase = rg * 128 + wv * 64;
  const u64 gm = 0xFFFFull << (q * 16);
  const u64 lanelow = (lane == 63) ? 0x7FFFFFFFFFFFFFFFull
                                   : ((1ull << (lane + 1)) - 1) >> 1;
  const u64 gml = gm & lanelow;
  const int row = lane & 15;        // drain role: row within half
  const int ls5 = lane >> 5;

  const u64 KINIT = ((u64)sortf(-INF_F) << 32);   // (-inf, ent=~0)
  u64 slot[4][4];
  float myth[4], th[4][4];
  #pragma unroll
  for (int h = 0; h < 4; ++h) {
    myth[h] = -INF_F;
    #pragma unroll
    for (int s = 0; s < 4; ++s) { slot[h][s] = KINIT; th[h][s] = -INF_F; }
  }

  // A fragments resident: 4 rowfrags x 8 ksteps x 8 bf16 = 128 VGPR
  bf16x8 a[4][8];
  #pragma unroll
  for (int h = 0; h < 4; ++h)
    #pragma unroll
    for (int s = 0; s < 8; ++s)
      a[h][s] = *(const bf16x8*)(spanbf
                  + (size_t)(rowbase + h * 16 + m) * 256 + s * 32 + q * 8);

  // stage chunk k (16 ents) into ring slot sl. LDS dest linear; source
  // XOR-pre-swizzled so read side uses (qq ^ (e&31)) addressing.
  auto issue = [&](int k, int sl) {
    const int cb = e_start + (k << 4);
    #pragma unroll
    for (int i = 0; i < 4; ++i) {
      int eo = wv * 8 + i * 2 + ls5;          // ent within chunk [0,16)
      int e  = (sl << 4) + eo;                // ring-local ent
      int ge = min(cb + eo, e_end - 1);
      int xoff = ((lane & 31) ^ (e & 31)) << 4;
      gload_lds16((const char*)entbf + (size_t)ge * 512 + xoff,
                  (char*)Elds + (sl << 13) + (wv << 12) + (i << 10));
    }
  };

  const int nch = (e_end - e_start + 15) >> 4;
  issue(0, 0);
  if (nch > 1) issue(1, 1);
  int cs = 0;                       // ring slot of current chunk

  for (int pc = 0; pc < nch; ++pc) {
    if (pc + 1 < nch) asm volatile("s_waitcnt vmcnt(4)" ::: "memory");
    else              asm volatile("s_waitcnt vmcnt(0)" ::: "memory");
    __builtin_amdgcn_sched_barrier(0);
    __builtin_amdgcn_s_barrier();   // chunk pc landed for BOTH waves;
                                    // both waves done computing pc-1
    {
      int s2 = cs + 2; if (s2 >= 3) s2 -= 3;
      if (pc + 2 < nch) issue(pc + 2, s2);   // depth-2: into pc-1's slot
    }

    // ---- compute chunk pc: 16 ents x 64 rows ----
    f32x4 acc[4];
    #pragma unroll
    for (int h = 0; h < 4; ++h) acc[h] = (f32x4){0.f, 0.f, 0.f, 0.f};
    const int el = (cs << 4) + m, sw = el & 31, bc = el << 5;
    #pragma unroll
    for (int s = 0; s < 8; ++s) {
      int qq = s * 4 + q;
      bf16x8 bfr = *(const bf16x8*)((const char*)Elds + ((bc | (qq ^ sw)) << 4));
      #pragma unroll
      for (int h = 0; h < 4; ++h)
        acc[h] = __builtin_amdgcn_mfma_f32_16x16x32_bf16(a[h][s], bfr, acc[h], 0, 0, 0);
    }
    const int gent = e_start + (pc << 4) + m;
    const bool valid = gent < e_end;

    #pragma unroll
    for (int h = 0; h < 4; ++h) {
      // gate: any row of this half beats its threshold?
      bool any = valid & ((acc[h][0] > th[h][0]) | (acc[h][1] > th[h][1]) |
                          (acc[h][2] > th[h][2]) | (acc[h][3] > th[h][3]));
      if (!__ballot(any)) continue;
      // full produce: per-row ballots + queue append (XOR-swizzled pos)
      u64 M[4];
      #pragma unroll
      for (int r = 0; r < 4; ++r) {
        bool hr = valid && (acc[h][r] > th[h][r]);
        M[r] = __ballot(hr);
        if (hr) {
          int pos = (int)__popcll(M[r] & gml);
          Q[wv][h * 16 + q4 + r][pos ^ (q4 + r)] =
              ((u64)sortf(acc[h][r]) << 32) | (u32)(~(u32)gent);
        }
      }
      // drain: 64 lanes, 4 lanes x 4 slots per row; Q reads pipelined
      u64 msk = (row & 2) ? ((row & 1) ? M[3] : M[2])
                          : ((row & 1) ? M[1] : M[0]);
      int cnt = (int)__popcll((msk >> ((row >> 2) << 4)) & 0xFFFFull);
      int cmax = cnt;
      #pragma unroll
      for (int o = 1; o < 16; o <<= 1)
        cmax = max(cmax, __shfl_xor(cmax, o));
      const u64* qrow = Q[wv][h * 16 + row];
      u64 candNext = qrow[row];     // round 0: index 0 ^ row
      for (int j = 0; j < cmax; ++j) {
        u64 cand = (j < cnt) ? candNext : 0;       // 0 never inserts
        candNext = qrow[((j + 1) & 15) ^ row];     // prefetch next round
        u64 m01 = slot[h][0] < slot[h][1] ? slot[h][0] : slot[h][1];
        u64 m23 = slot[h][2] < slot[h][3] ? slot[h][2] : slot[h][3];
        u64 lmin = m01 < m23 ? m01 : m23;
        u64 g = sx64(lmin, 16); if (g < lmin) lmin = g;
        g = sx64(lmin, 32); u64 gmin = (g < lmin) ? g : lmin;
        bool ins = cand > gmin;
        #pragma unroll
        for (int s2 = 0; s2 < 4; ++s2)
          if (ins && slot[h][s2] == gmin) slot[h][s2] = cand;
      }
      {  // refresh row 16th-value + producer thresholds
        u64 m01 = slot[h][0] < slot[h][1] ? slot[h][0] : slot[h][1];
        u64 m23 = slot[h][2] < slot[h][3] ? slot[h][2] : slot[h][3];
        u64 lmin = m01 < m23 ? m01 : m23;
        u64 g = sx64(lmin, 16); if (g < lmin) lmin = g;
        g = sx64(lmin, 32); if (g < lmin) lmin = g;
        myth[h] = unsortf((u32)(lmin >> 32));
        #pragma unroll
        for (int r = 0; r < 4; ++r) th[h][r] = __shfl(myth[h], q4 + r);
      }
    }
    cs = cs + 1 == 3 ? 0 : cs + 1;
  }

  // writeout: lane (sg,row) holds slots sg*4+s of row rowbase+h*16+row
  {
    const int sg = lane >> 4;
    #pragma unroll
    for (int h = 0; h < 4; ++h) {
      int r0 = rowbase + h * 16 + row;
      #pragma unroll
      for (int s = 0; s < 4; ++s) {
        u64 e0 = slot[h][s];
        int col = p * 16 + sg * 4 + s;
        Rpv[(size_t)r0 * 256 + col] = unsortf((u32)(e0 >> 32));
        Rpi[(size_t)r0 * 256 + col] = (int)(~(u32)e0);
      }
    }
  }
}

// ---------------------------------------------------------------------------
// K2b: exact top-16 of the 256 partition candidates per row (rank counting).
// grid = 2048 blocks x 4 waves (1 row/wave, 4 pairs/lane).
// ---------------------------------------------------------------------------
__global__ __launch_bounds__(256) void k2_merge(
    const float* __restrict__ Rpv, const int* __restrict__ Rpi,
    int* __restrict__ Ridx) {
  const int t = threadIdx.x, lane = t & 63, wv = t >> 6;
  const int row = blockIdx.x * 4 + wv;
  float v[4]; int e[4];
  #pragma unroll
  for (int pg = 0; pg < 4; ++pg) {
    v[pg] = Rpv[(size_t)row * 256 + pg * 64 + lane];
    e[pg] = Rpi[(size_t)row * 256 + pg * 64 + lane];
  }
  int c[4] = {0, 0, 0, 0};
  #pragma unroll
  for (int ps = 0; ps < 4; ++ps) {
    for (int i = 0; i < 64; ++i) {
      float ov = __shfl(v[ps], i); int oi = __shfl(e[ps], i);
      #pragma unroll
      for (int pd = 0; pd < 4; ++pd)
        c[pd] += (ov > v[pd] || (ov == v[pd] && oi < e[pd]));
    }
  }
  #pragma unroll
  for (int pg = 0; pg < 4; ++pg)
    if (c[pg] < 16) Ridx[(size_t)row * 16 + c[pg]] = e[pg];
}

// ---------------------------------------------------------------------------
// K3: batched-span GCN on the MATRIX CORES. grid = 2048 x 256 (4 waves);
// 4 spans/block (32 node rows). fp64 re-rank of 16 candidates (from exact
// fp32 out1 + ent) -> top-8. Star-mix commutes with the GEMM:
//   out = A·relu(A·X·W1 + b1)·W2 + b2,  A·(X·W) = (A·X)·W
// so both GEMMs run on RAW rows via bf16 MFMA (fp32 accum), and the mix is
// applied column-locally on the fp32 MFMA output.
// LDS: Abf (bf16 A-operand, 17.4 KB) + UN union{re-rank scratch | W-slab
// transposed bf16 (20.5 KB) | fp32 C-out (34.3 KB)} -> ~52 KB, 3 blocks/CU.
// MFMA fragment conventions identical to k2 (proven).
// ---------------------------------------------------------------------------
__global__ __launch_bounds__(256, 3) void k3_gcn(
    const float* __restrict__ out1, const float* __restrict__ ent,
    const int* __restrict__ Ridx,
    const float* __restrict__ W1, const float* __restrict__ b1,
    const float* __restrict__ W2, const float* __restrict__ b2,
    float* __restrict__ out2, int ne) {
  __shared__ __align__(16) char UN[34560];
  __shared__ __align__(16) u16 Abf[32][272];   // A operand bf16 (X, then H)
  __shared__ int cidx[4][16];
  __shared__ int chos[4][8];
  const int t = threadIdx.x;
  const int lane = t & 63, wv = t >> 6;
  const int m = lane & 15, q = lane >> 4;
  const int n0 = blockIdx.x * 4;

  // ---- phase 1: re-rank (fp64) -> chos[4][8]. scratch lives in UN. ----
  {
    float  (*SPR)[256] = (float (*)[256])UN;            // 4 KB
    double (*dpart)[4] = (double (*)[4])(UN + 4096);    // 2 KB
    double (*sims)[16] = (double (*)[16])(UN + 6144);   // 0.5 KB
    #pragma unroll
    for (int g = 0; g < 4; ++g)
      SPR[g][t] = out1[(size_t)(n0 + g) * 256 + t];
    if (t < 64) {
      int g = t >> 4, j = t & 15;
      int c = Ridx[(size_t)(n0 + g) * 16 + j];
      if ((unsigned)c >= (unsigned)ne) c = 0;   // defensive
      cidx[g][j] = c;
    }
    __syncthreads();

    {
      const int pr = t >> 2, sub = t & 3;
      const int g = pr >> 4, j = pr & 15;
      const float* er = ent + (size_t)cidx[g][j] * 256 + sub * 64;
      const float* sr = &SPR[g][sub * 64];
      double s = 0.0;
      #pragma unroll
      for (int i = 0; i < 64; i += 4) {
        float4 e4 = *(const float4*)&er[i];
        float4 s4 = *(const float4*)&sr[i];
        s += (double)e4.x * (double)s4.x;
        s += (double)e4.y * (double)s4.y;
        s += (double)e4.z * (double)s4.z;
        s += (double)e4.w * (double)s4.w;
      }
      dpart[pr][sub] = s;
    }
    __syncthreads();
    if (t < 64) {
      int g = t >> 4, j = t & 15;
      sims[g][j] = dpart[t][0] + dpart[t][1] + dpart[t][2] + dpart[t][3];
    }
    __syncthreads();
    if (t < 4) {
      unsigned used = 0;
      for (int o = 0; o < 8; ++o) {
        int best = -1; double bv = 0.0; int bi = 0;
        for (int j = 0; j < 16; ++j) {
          if (used & (1u << j)) continue;
          if (best < 0 || sims[t][j] > bv || (sims[t][j] == bv && cidx[t][j] < bi)) {
            best = j; bv = sims[t][j]; bi = cidx[t][j];
          }
        }
        used |= (1u << best);
        chos[t][o] = cidx[t][best];
      }
    }
    __syncthreads();
  }

  // ---- phase 2: gather 32 ent rows -> bf16 -> Abf (raw X, no mix) ----
  {
    const int r = t >> 3, cb = t & 7;
    const float* src = ent + (size_t)chos[r >> 3][r & 7] * 256 + cb * 32;
    u32 pk[16];
    #pragma unroll
    for (int i = 0; i < 8; ++i) {
      float4 v = *(const float4*)&src[i * 4];
      pk[2 * i]     = (u32)f2bf(v.x) | ((u32)f2bf(v.y) << 16);
      pk[2 * i + 1] = (u32)f2bf(v.z) | ((u32)f2bf(v.w) << 16);
    }
    uint4* dst = (uint4*)&Abf[r][cb * 32];
    #pragma unroll
    for (int i = 0; i < 4; ++i)
      dst[i] = make_uint4(pk[4 * i], pk[4 * i + 1], pk[4 * i + 2], pk[4 * i + 3]);
  }

  // ---- MFMA GEMM: C(32x256) = Abf(32x256) @ W(256x256), result -> Cl(UN)
  auto run_gemm = [&](const float* __restrict__ Wg) {
    f32x4 acc[2][4];
    #pragma unroll
    for (int mt = 0; mt < 2; ++mt)
      #pragma unroll
      for (int nt = 0; nt < 4; ++nt)
        acc[mt][nt] = (f32x4){0.f, 0.f, 0.f, 0.f};

    for (int s = 0; s < 8; ++s) {
      __syncthreads();               // UN free (prev reads done / Abf ready)
      {  // stage W-slab s: rows s*32..+32, transposed bf16. thread t = col t.
        const float* src = Wg + (size_t)(s * 32) * 256 + t;
        u32 pk[16];
        #pragma unroll
        for (int i = 0; i < 16; ++i) {
          float lo = src[(size_t)(2 * i) * 256];
          float hi = src[(size_t)(2 * i + 1) * 256];
          pk[i] = (u32)f2bf(lo) | ((u32)f2bf(hi) << 16);
        }
        uint4* dst = (uint4*)(UN + t * 80);    // Bt[col][40 u16], 80B rows
        #pragma unroll
        for (int i = 0; i < 4; ++i)
          dst[i] = make_uint4(pk[4 * i], pk[4 * i + 1], pk[4 * i + 2], pk[4 * i + 3]);
      }
      __syncthreads();               // Bt ready
      #pragma unroll
      for (int mt = 0; mt < 2; ++mt) {
        bf16x8 af = *(const bf16x8*)((const char*)Abf
                       + (mt * 16 + m) * 544 + s * 64 + q * 16);
        #pragma unroll
        for (int nt = 0; nt < 4; ++nt) {
          const int col = wv * 64 + nt * 16 + m;
          bf16x8 bf = *(const bf16x8*)(UN + col * 80 + q * 16);
          acc[mt][nt] = __builtin_amdgcn_mfma_f32_16x16x32_bf16(
              af, bf, acc[mt][nt], 0, 0, 0);
        }
      }
    }
    __syncthreads();                 // all MFMA reads of UN done -> Cl view
    #pragma unroll
    for (int mt = 0; mt < 2; ++mt)
      #pragma unroll
      for (int nt = 0; nt < 4; ++nt)
        #pragma unroll
        for (int r = 0; r < 4; ++r)
          *(float*)(UN + (((mt * 16 + q * 4 + r) * 268)
                          + (wv * 64 + nt * 16 + m)) * 4) = acc[mt][nt][r];
    __syncthreads();                 // Cl ready
  };

  // ---- GEMM1 + mix + b1 + relu -> H (bf16) back into Abf ----
  run_gemm(W1);
  {
    const float bb = b1[t];
    #pragma unroll
    for (int g = 0; g < 4; ++g) {
      float v[8];
      #pragma unroll
      for (int j = 0; j < 8; ++j)
        v[j] = *(const float*)(UN + ((g * 8 + j) * 268 + t) * 4);
      float ssum = 0.f;
      #pragma unroll
      for (int j = 1; j < 8; ++j) ssum += v[j];
      Abf[g * 8][t] = f2bf(fmaxf(v[0] * 0.125f + ssum * 0.25f + bb, 0.f));
      #pragma unroll
      for (int j = 1; j < 8; ++j)
        Abf[g * 8 + j][t] = f2bf(fmaxf(v[0] * 0.25f + v[j] * 0.5f + bb, 0.f));
    }
  }
  // (run_gemm's leading barrier separates these Cl reads / Abf writes
  //  from GEMM2's staging writes / Abf reads)

  // ---- GEMM2 + mix + b2 -> out2 ----
  run_gemm(W2);
  {
    const float bb = b2[t];
    #pragma unroll
    for (int g = 0; g < 4; ++g) {
      float v[8];
      #pragma unroll
      for (int j = 0; j < 8; ++j)
        v[j] = *(const float*)(UN + ((g * 8 + j) * 268 + t) * 4);
      float ssum = 0.f;
      #pragma unroll
      for (int j = 1; j < 8; ++j) ssum += v[j];
      float* ob = out2 + (size_t)(n0 + g) * 2048 + t;
      ob[0] = v[0] * 0.125f + ssum * 0.25f + bb;
      #pragma unroll
      for (int j = 1; j < 8; ++j)
        ob[(size_t)j * 256] = v[0] * 0.25f + v[j] * 0.5f + bb;
    }
  }
}

// ---------------------------------------------------------------------------
extern "C" void kernel_launch(void* const* d_in, const int* in_sizes, int n_in,
                              void* d_out, int out_size, void* d_ws, size_t ws_size,
                              hipStream_t stream) {
  const float* emb = (const float*)d_in[0];
  const float* ent = (const float*)d_in[1];
  const float* Wsp = (const float*)d_in[2];
  const float* bsp = (const float*)d_in[3];
  const float* W1  = (const float*)d_in[4];
  const float* b1  = (const float*)d_in[5];
  const float* W2  = (const float*)d_in[6];
  const float* b2  = (const float*)d_in[7];
  const int ne = in_sizes[1] / 256;   // 50000

  float* out  = (float*)d_out;
  float* out0 = out;                        // cls: 1024
  float* out1 = out + 1024;                 // span_repr: 8192*256
  float* out2 = out + 1024 + 2097152;       // subgraph_out: 64 MB region

  // scratch overlays on out2 (consumed before k3 overwrites; strict order):
  char* ov = (char*)out2;
  u16*   entbf  = (u16*)(ov);                     // 25.6 MB bf16 entity table
  u16*   spanbf = (u16*)(ov + 33554432);          //  4 MB bf16 span matrix
  float* Rpv    = (float*)(ov + 41943040);        //  8 MB partial topk vals
  int*   Rpi    = (int*)  (ov + 50331648);        //  8 MB partial topk idx
  int*   Ridx   = (int*)d_ws;                     // 512 KB final top-16 idx

  hipLaunchKernelGGL(k0_cvt, dim3((ne * 64 + 255) / 256), dim3(256), 0, stream,
                     ent, entbf, ne * 64);
  hipLaunchKernelGGL(k1_span, dim3(1024), dim3(256), 0, stream,
                     emb, Wsp, bsp, out0, out1, spanbf);
  hipLaunchKernelGGL(k2_mfma, dim3(1024), dim3(128), 0, stream,
                     spanbf, entbf, ne, Rpv, Rpi);
  hipLaunchKernelGGL(k2_merge, dim3(2048), dim3(256), 0, stream,
                     Rpv, Rpi, Ridx);
  hipLaunchKernelGGL(k3_gcn, dim3(2048), dim3(256), 0, stream,
                     out1, ent, Ridx, W1, b1, W2, b2, out2, ne);
}

// Round 8
// 729.967 us; speedup vs baseline: 1.0200x; 1.0200x over previous
//
#include <hip/hip_runtime.h>

typedef unsigned short u16;
typedef unsigned int   u32;
typedef unsigned long long u64;
typedef short bf16x8 __attribute__((ext_vector_type(8)));
typedef float f32x4  __attribute__((ext_vector_type(4)));

#define INF_F __builtin_inff()

__device__ __forceinline__ u16 f2bf(float f) {
  u32 u = __float_as_uint(f);
  return (u16)((u + 0x7FFFu + ((u >> 16) & 1u)) >> 16);   // RNE
}

// float -> monotonic-sortable u32 (bigger = larger float)
__device__ __forceinline__ u32 sortf(float f) {
  u32 u = __float_as_uint(f);
  return u ^ ((u32)((int)u >> 31) | 0x80000000u);
}
__device__ __forceinline__ float unsortf(u32 s) {
  u32 u = s ^ ((s & 0x80000000u) ? 0x80000000u : 0xFFFFFFFFu);
  return __uint_as_float(u);
}
__device__ __forceinline__ u64 sx64(u64 v, int m) {
  u32 lo = __shfl_xor((u32)v, m);
  u32 hi = __shfl_xor((u32)(v >> 32), m);
  return ((u64)hi << 32) | lo;
}

__device__ __forceinline__ void gload_lds16(const void* g, void* l) {
  __builtin_amdgcn_global_load_lds(
      (const __attribute__((address_space(1))) u32*)g,
      (__attribute__((address_space(3))) u32*)l, 16, 0, 0);
}

// ---------------------------------------------------------------------------
// K0: entity table fp32 -> bf16 (RNE), row-major [ne][256]. n4 = ne*64.
// ---------------------------------------------------------------------------
__global__ __launch_bounds__(256) void k0_cvt(
    const float* __restrict__ src, u16* __restrict__ dst, int n4) {
  int id = blockIdx.x * 256 + threadIdx.x;
  if (id >= n4) return;
  float4 v = ((const float4*)src)[id];
  ((ushort4*)dst)[id] = make_ushort4(f2bf(v.x), f2bf(v.y), f2bf(v.z), f2bf(v.w));
}

// ---------------------------------------------------------------------------
// K1: span_max + span_repr fp32 (+ bf16 copy for MFMA prefilter).
// grid = 1024 blocks (b,s), 256 threads.
// ---------------------------------------------------------------------------
__global__ __launch_bounds__(256) void k1_span(
    const float* __restrict__ emb, const float* __restrict__ Wsp,
    const float* __restrict__ bsp,
    float* __restrict__ out0, float* __restrict__ out1,
    u16* __restrict__ spanbf) {
  __shared__ float SM[8][256];
  __shared__ float CLS[256];
  const int bid = blockIdx.x;          // b*256 + s
  const int b = bid >> 8, s = bid & 255;
  const int t = threadIdx.x;
  const float* eb = emb + (size_t)b * 65536;

  CLS[t] = eb[t];
  if (s == 0) out0[b * 256 + t] = eb[t];

  float m = eb[s * 256 + t];
  SM[0][t] = m;
  #pragma unroll
  for (int w = 1; w < 8; ++w) {
    if (s + w < 256) m = fmaxf(m, eb[(s + w) * 256 + t]);
    SM[w][t] = m;
  }
  __syncthreads();

  float cc = 0.f;
  for (int k = 0; k < 256; k += 4) {
    float4 cq = *(const float4*)&CLS[k];
    cc += cq.x * Wsp[(size_t)(256 + k + 0) * 256 + t];
    cc += cq.y * Wsp[(size_t)(256 + k + 1) * 256 + t];
    cc += cq.z * Wsp[(size_t)(256 + k + 2) * 256 + t];
    cc += cq.w * Wsp[(size_t)(256 + k + 3) * 256 + t];
  }
  float acc[8];
  const float base = bsp[t] + cc;
  #pragma unroll
  for (int w = 0; w < 8; ++w) acc[w] = base;

  for (int k = 0; k < 256; k += 4) {
    float w0 = Wsp[(size_t)(k + 0) * 256 + t];
    float w1 = Wsp[(size_t)(k + 1) * 256 + t];
    float w2 = Wsp[(size_t)(k + 2) * 256 + t];
    float w3 = Wsp[(size_t)(k + 3) * 256 + t];
    #pragma unroll
    for (int w = 0; w < 8; ++w) {
      float4 smq = *(const float4*)&SM[w][k];
      acc[w] += smq.x * w0; acc[w] += smq.y * w1;
      acc[w] += smq.z * w2; acc[w] += smq.w * w3;
    }
  }
  const float wm = Wsp[(size_t)512 * 256 + t];
  #pragma unroll
  for (int w = 0; w < 8; ++w) {
    float val = acc[w] + (float)(w + 1) * wm;
    size_t idx = ((size_t)w * 1024 + bid) * 256 + t;
    out1[idx] = val;
    spanbf[idx] = f2bf(val);
  }
}

// ---------------------------------------------------------------------------
// K2: bf16 MFMA sims prefilter + per-row top-16, wave-parallel register slots.
// grid = 2048 blocks x 128 threads; p = blockIdx&15 (16 partitions; p&7 =
// XCD -> 2 slices = 3.2 MB per XCD L2), rg = blockIdx>>4 (128 rowgroups of
// 64 rows). 32 rows/wave (2 A-fragsets, 64 VGPR), LDS exactly 20 KB ->
// 8 blocks/CU = 16 waves/CU = 4 waves/SIMD (latency-hiding TLP; was the
// binding limit at 2/SIMD).
// Staging: global_load_lds, pre-swizzled source / linear LDS dest, ring-2
// (chunk = 16 ents = 8 KB): {vmcnt(0); barrier; issue(pc+1) into the slot
// freed by pc-1 (barrier-guaranteed); compute(pc)}. Loads get one full
// phase of cover. One barrier per chunk.
// Top-16 slots in registers as sortable u64 keys, 4 lanes x 4 slots/row.
// Q queue [2][32][8] XOR-swizzled; cnt>8 handled by rare 2-batch drain
// (deferred producers hold keys in registers).
// Exactness restored by K3 fp64 re-rank.
// ---------------------------------------------------------------------------
__global__ __launch_bounds__(128, 4) void k2_mfma(
    const u16* __restrict__ spanbf, const u16* __restrict__ entbf, int ne,
    float* __restrict__ Rpv, int* __restrict__ Rpi) {
  __shared__ u32 Elds[4096];        // 16 KB: ring-2 x 16 ents x 256 bf16
  __shared__ u64 Q[2][32][8];       //  4 KB: per-row queue, XOR-swizzled
  const int t = threadIdx.x, lane = t & 63, wv = t >> 6;
  const int m = lane & 15, q = lane >> 4, q4 = q * 4;
  const int p = blockIdx.x & 15, rg = blockIdx.x >> 4;
  const int psz = (ne + 15) >> 4;
  const int e_start = p * psz;
  const int e_end = min(ne, e_start + psz);
  const int rowbase = rg * 64 + wv * 32;
  const u64 gm = 0xFFFFull << (q * 16);
  const u64 lanelow = (lane == 63) ? 0x7FFFFFFFFFFFFFFFull
                                   : ((1ull << (lane + 1)) - 1) >> 1;
  const u64 gml = gm & lanelow;
  const int row = lane & 15;        // drain role: row within half
  const int ls5 = lane >> 5;

  const u64 KINIT = ((u64)sortf(-INF_F) << 32);   // (-inf, ent=~0)
  u64 slot[2][4];
  float myth[2], th[2][4];
  #pragma unroll
  for (int h = 0; h < 2; ++h) {
    myth[h] = -INF_F;
    #pragma unroll
    for (int s = 0; s < 4; ++s) { slot[h][s] = KINIT; th[h][s] = -INF_F; }
  }

  // A fragments resident: 2 rowfrags x 8 ksteps x 8 bf16 = 64 VGPR
  bf16x8 a[2][8];
  #pragma unroll
  for (int h = 0; h < 2; ++h)
    #pragma unroll
    for (int s = 0; s < 8; ++s)
      a[h][s] = *(const bf16x8*)(spanbf
                  + (size_t)(rowbase + h * 16 + m) * 256 + s * 32 + q * 8);

  // stage chunk k (16 ents) into ring slot sl. LDS dest linear; source
  // XOR-pre-swizzled so read side uses (qq ^ (e&31)) addressing.
  auto issue = [&](int k, int sl) {
    const int cb = e_start + (k << 4);
    #pragma unroll
    for (int i = 0; i < 4; ++i) {
      int eo = wv * 8 + i * 2 + ls5;          // ent within chunk [0,16)
      int e  = (sl << 4) + eo;                // ring-local ent
      int ge = min(cb + eo, e_end - 1);
      int xoff = ((lane & 31) ^ (e & 31)) << 4;
      gload_lds16((const char*)entbf + (size_t)ge * 512 + xoff,
                  (char*)Elds + (sl << 13) + (wv << 12) + (i << 10));
    }
  };

  const int nch = (e_end - e_start + 15) >> 4;
  issue(0, 0);

  for (int pc = 0; pc < nch; ++pc) {
    const int cs = pc & 1;
    asm volatile("s_waitcnt vmcnt(0)" ::: "memory");   // own chunk-pc loads
    __builtin_amdgcn_sched_barrier(0);
    __builtin_amdgcn_s_barrier();   // chunk pc landed for BOTH waves;
                                    // both waves done computing pc-1
    if (pc + 1 < nch) issue(pc + 1, cs ^ 1);   // slot freed by chunk pc-1

    // ---- compute chunk pc: 16 ents x 32 rows ----
    f32x4 acc[2];
    #pragma unroll
    for (int h = 0; h < 2; ++h) acc[h] = (f32x4){0.f, 0.f, 0.f, 0.f};
    const int el = (cs << 4) + m, sw = el & 31, bc = el << 5;
    #pragma unroll
    for (int s = 0; s < 8; ++s) {
      int qq = s * 4 + q;
      bf16x8 bfr = *(const bf16x8*)((const char*)Elds + ((bc | (qq ^ sw)) << 4));
      #pragma unroll
      for (int h = 0; h < 2; ++h)
        acc[h] = __builtin_amdgcn_mfma_f32_16x16x32_bf16(a[h][s], bfr, acc[h], 0, 0, 0);
    }
    const int gent = e_start + (pc << 4) + m;
    const bool valid = gent < e_end;

    #pragma unroll
    for (int h = 0; h < 2; ++h) {
      // gate: any row of this half beats its threshold?
      bool any = valid & ((acc[h][0] > th[h][0]) | (acc[h][1] > th[h][1]) |
                          (acc[h][2] > th[h][2]) | (acc[h][3] > th[h][3]));
      if (!__ballot(any)) continue;
      // full produce: per-row ballots + queue append (XOR-swizzled pos).
      // pos >= 8 deferred to batch 2 (rare; early chunks only).
      u64 M[4]; u64 key[4]; int ps_[4]; bool hit[4];
      #pragma unroll
      for (int r = 0; r < 4; ++r) {
        hit[r] = valid && (acc[h][r] > th[h][r]);
        M[r] = __ballot(hit[r]);
        key[r] = ((u64)sortf(acc[h][r]) << 32) | (u32)(~(u32)gent);
        ps_[r] = (int)__popcll(M[r] & gml);
        if (hit[r] && ps_[r] < 8)
          Q[wv][h * 16 + q4 + r][(ps_[r] ^ (q4 + r)) & 7] = key[r];
      }
      // drain: 64 lanes, 4 lanes x 4 slots per row
      u64 msk = (row & 2) ? ((row & 1) ? M[3] : M[2])
                          : ((row & 1) ? M[1] : M[0]);
      int cnt = (int)__popcll((msk >> ((row >> 2) << 4)) & 0xFFFFull);
      int cmax = cnt;
      #pragma unroll
      for (int o = 1; o < 16; o <<= 1)
        cmax = max(cmax, __shfl_xor(cmax, o));
      const u64* qrow = Q[wv][h * 16 + row];
      const int rx = row & 7;
      int cm1 = min(cmax, 8);
      for (int j = 0; j < cm1; ++j) {
        u64 cand = (j < cnt) ? qrow[(j ^ rx) & 7] : 0;   // 0 never inserts
        u64 m01 = slot[h][0] < slot[h][1] ? slot[h][0] : slot[h][1];
        u64 m23 = slot[h][2] < slot[h][3] ? slot[h][2] : slot[h][3];
        u64 lmin = m01 < m23 ? m01 : m23;
        u64 g = sx64(lmin, 16); if (g < lmin) lmin = g;
        g = sx64(lmin, 32); u64 gmin = (g < lmin) ? g : lmin;
        bool ins = cand > gmin;
        #pragma unroll
        for (int s2 = 0; s2 < 4; ++s2)
          if (ins && slot[h][s2] == gmin) slot[h][s2] = cand;
      }
      if (cmax > 8) {      // batch 2 (wave-uniform branch; rare)
        #pragma unroll
        for (int r = 0; r < 4; ++r)
          if (hit[r] && ps_[r] >= 8)
            Q[wv][h * 16 + q4 + r][((ps_[r] - 8) ^ (q4 + r)) & 7] = key[r];
        for (int j = 8; j < cmax; ++j) {
          u64 cand = (j < cnt) ? qrow[((j - 8) ^ rx) & 7] : 0;
          u64 m01 = slot[h][0] < slot[h][1] ? slot[h][0] : slot[h][1];
          u64 m23 = slot[h][2] < slot[h][3] ? slot[h][2] : slot[h][3];
          u64 lmin = m01 < m23 ? m01 : m23;
          u64 g = sx64(lmin, 16); if (g < lmin) lmin = g;
          g = sx64(lmin, 32); u64 gmin = (g < lmin) ? g : lmin;
          bool ins = cand > gmin;
          #pragma unroll
          for (int s2 = 0; s2 < 4; ++s2)
            if (ins && slot[h][s2] == gmin) slot[h][s2] = cand;
        }
      }
      {  // refresh row 16th-value + producer thresholds
        u64 m01 = slot[h][0] < slot[h][1] ? slot[h][0] : slot[h][1];
        u64 m23 = slot[h][2] < slot[h][3] ? slot[h][2] : slot[h][3];
        u64 lmin = m01 < m23 ? m01 : m23;
        u64 g = sx64(lmin, 16); if (g < lmin) lmin = g;
        g = sx64(lmin, 32); if (g < lmin) lmin = g;
        myth[h] = unsortf((u32)(lmin >> 32));
        #pragma unroll
        for (int r = 0; r < 4; ++r) th[h][r] = __shfl(myth[h], q4 + r);
      }
    }
  }

  // writeout: lane (sg,row) holds slots sg*4+s of row rowbase+h*16+row
  {
    const int sg = lane >> 4;
    #pragma unroll
    for (int h = 0; h < 2; ++h) {
      int r0 = rowbase + h * 16 + row;
      #pragma unroll
      for (int s = 0; s < 4; ++s) {
        u64 e0 = slot[h][s];
        int col = p * 16 + sg * 4 + s;
        Rpv[(size_t)r0 * 256 + col] = unsortf((u32)(e0 >> 32));
        Rpi[(size_t)r0 * 256 + col] = (int)(~(u32)e0);
      }
    }
  }
}

// ---------------------------------------------------------------------------
// K2b: exact top-16 of the 256 partition candidates per row (rank counting).
// grid = 2048 blocks x 4 waves (1 row/wave, 4 pairs/lane).
// ---------------------------------------------------------------------------
__global__ __launch_bounds__(256) void k2_merge(
    const float* __restrict__ Rpv, const int* __restrict__ Rpi,
    int* __restrict__ Ridx) {
  const int t = threadIdx.x, lane = t & 63, wv = t >> 6;
  const int row = blockIdx.x * 4 + wv;
  float v[4]; int e[4];
  #pragma unroll
  for (int pg = 0; pg < 4; ++pg) {
    v[pg] = Rpv[(size_t)row * 256 + pg * 64 + lane];
    e[pg] = Rpi[(size_t)row * 256 + pg * 64 + lane];
  }
  int c[4] = {0, 0, 0, 0};
  #pragma unroll
  for (int ps = 0; ps < 4; ++ps) {
    for (int i = 0; i < 64; ++i) {
      float ov = __shfl(v[ps], i); int oi = __shfl(e[ps], i);
      #pragma unroll
      for (int pd = 0; pd < 4; ++pd)
        c[pd] += (ov > v[pd] || (ov == v[pd] && oi < e[pd]));
    }
  }
  #pragma unroll
  for (int pg = 0; pg < 4; ++pg)
    if (c[pg] < 16) Ridx[(size_t)row * 16 + c[pg]] = e[pg];
}

// ---------------------------------------------------------------------------
// K3: batched-span GCN on the MATRIX CORES. grid = 2048 x 256 (4 waves);
// 4 spans/block (32 node rows). fp64 re-rank of 16 candidates (from exact
// fp32 out1 + ent) -> top-8. Star-mix commutes with the GEMM:
//   out = A·relu(A·X·W1 + b1)·W2 + b2,  A·(X·W) = (A·X)·W
// so both GEMMs run on RAW rows via bf16 MFMA (fp32 accum), and the mix is
// applied column-locally on the fp32 MFMA output.
// LDS: Abf (bf16 A-operand, 17.4 KB) + UN union{re-rank scratch | W-slab
// transposed bf16 (20.5 KB) | fp32 C-out (34.3 KB)} -> ~52 KB, 3 blocks/CU.
// MFMA fragment conventions identical to k2 (proven).
// ---------------------------------------------------------------------------
__global__ __launch_bounds__(256, 3) void k3_gcn(
    const float* __restrict__ out1, const float* __restrict__ ent,
    const int* __restrict__ Ridx,
    const float* __restrict__ W1, const float* __restrict__ b1,
    const float* __restrict__ W2, const float* __restrict__ b2,
    float* __restrict__ out2, int ne) {
  __shared__ __align__(16) char UN[34560];
  __shared__ __align__(16) u16 Abf[32][272];   // A operand bf16 (X, then H)
  __shared__ int cidx[4][16];
  __shared__ int chos[4][8];
  const int t = threadIdx.x;
  const int lane = t & 63, wv = t >> 6;
  const int m = lane & 15, q = lane >> 4;
  const int n0 = blockIdx.x * 4;

  // ---- phase 1: re-rank (fp64) -> chos[4][8]. scratch lives in UN. ----
  {
    float  (*SPR)[256] = (float (*)[256])UN;            // 4 KB
    double (*dpart)[4] = (double (*)[4])(UN + 4096);    // 2 KB
    double (*sims)[16] = (double (*)[16])(UN + 6144);   // 0.5 KB
    #pragma unroll
    for (int g = 0; g < 4; ++g)
      SPR[g][t] = out1[(size_t)(n0 + g) * 256 + t];
    if (t < 64) {
      int g = t >> 4, j = t & 15;
      int c = Ridx[(size_t)(n0 + g) * 16 + j];
      if ((unsigned)c >= (unsigned)ne) c = 0;   // defensive
      cidx[g][j] = c;
    }
    __syncthreads();

    {
      const int pr = t >> 2, sub = t & 3;
      const int g = pr >> 4, j = pr & 15;
      const float* er = ent + (size_t)cidx[g][j] * 256 + sub * 64;
      const float* sr = &SPR[g][sub * 64];
      double s = 0.0;
      #pragma unroll
      for (int i = 0; i < 64; i += 4) {
        float4 e4 = *(const float4*)&er[i];
        float4 s4 = *(const float4*)&sr[i];
        s += (double)e4.x * (double)s4.x;
        s += (double)e4.y * (double)s4.y;
        s += (double)e4.z * (double)s4.z;
        s += (double)e4.w * (double)s4.w;
      }
      dpart[pr][sub] = s;
    }
    __syncthreads();
    if (t < 64) {
      int g = t >> 4, j = t & 15;
      sims[g][j] = dpart[t][0] + dpart[t][1] + dpart[t][2] + dpart[t][3];
    }
    __syncthreads();
    if (t < 4) {
      unsigned used = 0;
      for (int o = 0; o < 8; ++o) {
        int best = -1; double bv = 0.0; int bi = 0;
        for (int j = 0; j < 16; ++j) {
          if (used & (1u << j)) continue;
          if (best < 0 || sims[t][j] > bv || (sims[t][j] == bv && cidx[t][j] < bi)) {
            best = j; bv = sims[t][j]; bi = cidx[t][j];
          }
        }
        used |= (1u << best);
        chos[t][o] = cidx[t][best];
      }
    }
    __syncthreads();
  }

  // ---- phase 2: gather 32 ent rows -> bf16 -> Abf (raw X, no mix) ----
  {
    const int r = t >> 3, cb = t & 7;
    const float* src = ent + (size_t)chos[r >> 3][r & 7] * 256 + cb * 32;
    u32 pk[16];
    #pragma unroll
    for (int i = 0; i < 8; ++i) {
      float4 v = *(const float4*)&src[i * 4];
      pk[2 * i]     = (u32)f2bf(v.x) | ((u32)f2bf(v.y) << 16);
      pk[2 * i + 1] = (u32)f2bf(v.z) | ((u32)f2bf(v.w) << 16);
    }
    uint4* dst = (uint4*)&Abf[r][cb * 32];
    #pragma unroll
    for (int i = 0; i < 4; ++i)
      dst[i] = make_uint4(pk[4 * i], pk[4 * i + 1], pk[4 * i + 2], pk[4 * i + 3]);
  }

  // ---- MFMA GEMM: C(32x256) = Abf(32x256) @ W(256x256), result -> Cl(UN)
  auto run_gemm = [&](const float* __restrict__ Wg) {
    f32x4 acc[2][4];
    #pragma unroll
    for (int mt = 0; mt < 2; ++mt)
      #pragma unroll
      for (int nt = 0; nt < 4; ++nt)
        acc[mt][nt] = (f32x4){0.f, 0.f, 0.f, 0.f};

    for (int s = 0; s < 8; ++s) {
      __syncthreads();               // UN free (prev reads done / Abf ready)
      {  // stage W-slab s: rows s*32..+32, transposed bf16. thread t = col t.
        const float* src = Wg + (size_t)(s * 32) * 256 + t;
        u32 pk[16];
        #pragma unroll
        for (int i = 0; i < 16; ++i) {
          float lo = src[(size_t)(2 * i) * 256];
          float hi = src[(size_t)(2 * i + 1) * 256];
          pk[i] = (u32)f2bf(lo) | ((u32)f2bf(hi) << 16);
        }
        uint4* dst = (uint4*)(UN + t * 80);    // Bt[col][40 u16], 80B rows
        #pragma unroll
        for (int i = 0; i < 4; ++i)
          dst[i] = make_uint4(pk[4 * i], pk[4 * i + 1], pk[4 * i + 2], pk[4 * i + 3]);
      }
      __syncthreads();               // Bt ready
      #pragma unroll
      for (int mt = 0; mt < 2; ++mt) {
        bf16x8 af = *(const bf16x8*)((const char*)Abf
                       + (mt * 16 + m) * 544 + s * 64 + q * 16);
        #pragma unroll
        for (int nt = 0; nt < 4; ++nt) {
          const int col = wv * 64 + nt * 16 + m;
          bf16x8 bf = *(const bf16x8*)(UN + col * 80 + q * 16);
          acc[mt][nt] = __builtin_amdgcn_mfma_f32_16x16x32_bf16(
              af, bf, acc[mt][nt], 0, 0, 0);
        }
      }
    }
    __syncthreads();                 // all MFMA reads of UN done -> Cl view
    #pragma unroll
    for (int mt = 0; mt < 2; ++mt)
      #pragma unroll
      for (int nt = 0; nt < 4; ++nt)
        #pragma unroll
        for (int r = 0; r < 4; ++r)
          *(float*)(UN + (((mt * 16 + q * 4 + r) * 268)
                          + (wv * 64 + nt * 16 + m)) * 4) = acc[mt][nt][r];
    __syncthreads();                 // Cl ready
  };

  // ---- GEMM1 + mix + b1 + relu -> H (bf16) back into Abf ----
  run_gemm(W1);
  {
    const float bb = b1[t];
    #pragma unroll
    for (int g = 0; g < 4; ++g) {
      float v[8];
      #pragma unroll
      for (int j = 0; j < 8; ++j)
        v[j] = *(const float*)(UN + ((g * 8 + j) * 268 + t) * 4);
      float ssum = 0.f;
      #pragma unroll
      for (int j = 1; j < 8; ++j) ssum += v[j];
      Abf[g * 8][t] = f2bf(fmaxf(v[0] * 0.125f + ssum * 0.25f + bb, 0.f));
      #pragma unroll
      for (int j = 1; j < 8; ++j)
        Abf[g * 8 + j][t] = f2bf(fmaxf(v[0] * 0.25f + v[j] * 0.5f + bb, 0.f));
    }
  }
  // (run_gemm's leading barrier separates these Cl reads / Abf writes
  //  from GEMM2's staging writes / Abf reads)

  // ---- GEMM2 + mix + b2 -> out2 ----
  run_gemm(W2);
  {
    const float bb = b2[t];
    #pragma unroll
    for (int g = 0; g < 4; ++g) {
      float v[8];
      #pragma unroll
      for (int j = 0; j < 8; ++j)
        v[j] = *(const float*)(UN + ((g * 8 + j) * 268 + t) * 4);
      float ssum = 0.f;
      #pragma unroll
      for (int j = 1; j < 8; ++j) ssum += v[j];
      float* ob = out2 + (size_t)(n0 + g) * 2048 + t;
      ob[0] = v[0] * 0.125f + ssum * 0.25f + bb;
      #pragma unroll
      for (int j = 1; j < 8; ++j)
        ob[(size_t)j * 256] = v[0] * 0.25f + v[j] * 0.5f + bb;
    }
  }
}

// ---------------------------------------------------------------------------
extern "C" void kernel_launch(void* const* d_in, const int* in_sizes, int n_in,
                              void* d_out, int out_size, void* d_ws, size_t ws_size,
                              hipStream_t stream) {
  const float* emb = (const float*)d_in[0];
  const float* ent = (const float*)d_in[1];
  const float* Wsp = (const float*)d_in[2];
  const float* bsp = (const float*)d_in[3];
  const float* W1  = (const float*)d_in[4];
  const float* b1  = (const float*)d_in[5];
  const float* W2  = (const float*)d_in[6];
  const float* b2  = (const float*)d_in[7];
  const int ne = in_sizes[1] / 256;   // 50000

  float* out  = (float*)d_out;
  float* out0 = out;                        // cls: 1024
  float* out1 = out + 1024;                 // span_repr: 8192*256
  float* out2 = out + 1024 + 2097152;       // subgraph_out: 64 MB region

  // scratch overlays on out2 (consumed before k3 overwrites; strict order):
  char* ov = (char*)out2;
  u16*   entbf  = (u16*)(ov);                     // 25.6 MB bf16 entity table
  u16*   spanbf = (u16*)(ov + 33554432);          //  4 MB bf16 span matrix
  float* Rpv    = (float*)(ov + 41943040);        //  8 MB partial topk vals
  int*   Rpi    = (int*)  (ov + 50331648);        //  8 MB partial topk idx
  int*   Ridx   = (int*)d_ws;                     // 512 KB final top-16 idx

  hipLaunchKernelGGL(k0_cvt, dim3((ne * 64 + 255) / 256), dim3(256), 0, stream,
                     ent, entbf, ne * 64);
  hipLaunchKernelGGL(k1_span, dim3(1024), dim3(256), 0, stream,
                     emb, Wsp, bsp, out0, out1, spanbf);
  hipLaunchKernelGGL(k2_mfma, dim3(2048), dim3(128), 0, stream,
                     spanbf, entbf, ne, Rpv, Rpi);
  hipLaunchKernelGGL(k2_merge, dim3(2048), dim3(256), 0, stream,
                     Rpv, Rpi, Ridx);
  hipLaunchKernelGGL(k3_gcn, dim3(2048), dim3(256), 0, stream,
                     out1, ent, Ridx, W1, b1, W2, b2, out2, ne);
}